// Round 6
// baseline (1283.534 us; speedup 1.0000x reference)
//
#include <hip/hip_runtime.h>
#include <hip/hip_bf16.h>
#include <hip/hip_fp16.h>

// Problem constants
// x: (16,64,1024,12) f32, support: (16,3,1024,1024) f32
// out: (16,64,1024,12) f32
#define NB 16
#define V 1024
#define LL 12
#define C64 64
#define SL 3
#define CL 768        // 64*12
#define KTOT 12288    // 12*1024
#define MARKOFF -1e20f

typedef _Float16 f16x8 __attribute__((ext_vector_type(8)));
typedef __attribute__((ext_vector_type(4))) float f32x4;

// fp32 -> fp16 bits (RN). All quantized tensors (x, G, Y, A) are
// small-magnitude; fp16 gives 8x lower rounding error than bf16 at the same
// MFMA rate.
static __device__ __forceinline__ unsigned short f2h(float f) {
  __half h = __float2half(f);
  return __builtin_bit_cast(unsigned short, h);
}

// async global->LDS direct staging, 16B per lane.
// LDS dest must be wave-uniform base + lane*16 (it is: byte offset = t*16).
typedef const __attribute__((address_space(1))) unsigned int gas_u32;
typedef __attribute__((address_space(3))) unsigned int las_u32;
static __device__ __forceinline__ void gld16(const void* g, void* l) {
  __builtin_amdgcn_global_load_lds((gas_u32*)g, (las_u32*)l, 16, 0, 0);
}

// 64-bit cross-lane helpers (2x32-bit shuffles)
static __device__ __forceinline__ unsigned long long shflx64(unsigned long long v, int m) {
  unsigned lo = __shfl_xor((unsigned)v, m);
  unsigned hi = __shfl_xor((unsigned)(v >> 32), m);
  return ((unsigned long long)hi << 32) | lo;
}
static __device__ __forceinline__ unsigned long long shfl64get(unsigned long long v, int srcLane) {
  unsigned lo = __shfl((unsigned)v, srcLane);
  unsigned hi = __shfl((unsigned)(v >> 32), srcLane);
  return ((unsigned long long)hi << 32) | lo;
}
// monotone key <-> float
static __device__ __forceinline__ float k2f(unsigned kk) {
  unsigned u = (kk & 0x80000000u) ? (kk & 0x7FFFFFFFu) : ~kk;
  return __uint_as_float(u);
}

// ---------------------------------------------------------------------------
// k_prep: D = F0*W0 (fp32), Gt[(ig*64+o)][c] = fp16( sum_c2 Wf[o,64(i+1)+c2]*Ws[i][c2][64g+c] ),
//         cb[o] = bf[o] + F0*b0 + sum_i F_{i+1}*bs[i]
__global__ __launch_bounds__(256) void k_prep(const float* __restrict__ W0,
                                              const float* __restrict__ b0,
                                              const float* __restrict__ Ws,
                                              const float* __restrict__ bs,
                                              const float* __restrict__ Wf,
                                              const float* __restrict__ bf,
                                              float* __restrict__ D,
                                              float* __restrict__ cb,
                                              unsigned short* __restrict__ Gt) {
  int b = blockIdx.x;
  int t = threadIdx.x;
  int o = t >> 2, cp = t & 3;
  if (b < 12) {
    int i = b >> 2, g = b & 3;
    for (int c = cp * 16; c < cp * 16 + 16; c++) {
      float acc = 0.f;
      for (int c2 = 0; c2 < 64; c2++)
        acc += Wf[o * 256 + 64 * (i + 1) + c2] * Ws[i * 16384 + c2 * 256 + g * 64 + c];
      Gt[(size_t)(b * 64 + o) * 64 + c] = f2h(acc);
    }
  } else {
    for (int c = cp * 16; c < cp * 16 + 16; c++) {
      float acc = 0.f;
      for (int c2 = 0; c2 < 64; c2++)
        acc += Wf[o * 256 + c2] * W0[c2 * 64 + c];
      D[o * 64 + c] = acc;
    }
    if (t < 64) {
      float acc = bf[t];
      for (int c2 = 0; c2 < 64; c2++) acc += Wf[t * 256 + c2] * b0[c2];
      for (int i = 0; i < 3; i++)
        for (int c2 = 0; c2 < 64; c2++) acc += Wf[t * 256 + 64 * (i + 1) + c2] * bs[i * 64 + c2];
      cb[t] = acc;
    }
  }
}

// ---------------------------------------------------------------------------
// k_stats v2: ONE WAVE PER ROW, barrier-light, atomic-free, histogram-free.
__global__ __launch_bounds__(256) void k_stats(const float* __restrict__ support,
                                               float* __restrict__ stats) {
  int t = threadIdx.x;
  int lane = t & 63, wid = t >> 6;
  int row = blockIdx.x * 4 + wid;  // (n*3+i)*1024 + v
  const float* a = support + (size_t)row * 1024;

  __shared__ unsigned long long cand[4][128];

  float va[16];
  const float4* a4 = (const float4*)a;
#pragma unroll
  for (int j = 0; j < 4; j++) {
    float4 f = a4[lane + 64 * j];
    va[j * 4 + 0] = f.x; va[j * 4 + 1] = f.y; va[j * 4 + 2] = f.z; va[j * 4 + 3] = f.w;
  }

  float m = va[0];
#pragma unroll
  for (int q = 1; q < 16; q++) m = fmaxf(m, va[q]);
#pragma unroll
  for (int off = 32; off; off >>= 1) m = fmaxf(m, __shfl_xor(m, off));

  float zf = 0.f;
#pragma unroll
  for (int q = 0; q < 16; q++) zf += __expf(va[q] - m);
#pragma unroll
  for (int off = 32; off; off >>= 1) zf += __shfl_xor(zf, off);

  unsigned ky[16];
#pragma unroll
  for (int q = 0; q < 16; q++) {
    unsigned u = __float_as_uint(va[q]);
    ky[q] = (u & 0x80000000u) ? ~u : (u | 0x80000000u);
  }

  unsigned Klo = 0u, Khi = 0xFFFFFFFFu;
  unsigned K = 0xBFB33333u;  // key(1.4f) seed
  int c = 0;
  bool ok = false;
  for (int it = 0; it < 40; ++it) {
    int cl = 0;
#pragma unroll
    for (int q = 0; q < 16; q++) cl += (ky[q] > K) ? 1 : 0;
    c = cl;
#pragma unroll
    for (int off = 32; off; off >>= 1) c += __shfl_xor(c, off);
    if (c >= 40 && c <= 128) { ok = true; break; }
    if (c > 128) Klo = K; else Khi = K;
    if (Khi - Klo <= 1u) break;
    K = Klo + ((Khi - Klo) >> 1);
  }
  bool special = !ok;
  if (special) {
    K = Khi;
    int cl = 0;
#pragma unroll
    for (int q = 0; q < 16; q++) cl += (ky[q] > K) ? 1 : 0;
    c = cl;
#pragma unroll
    for (int off = 32; off; off >>= 1) c += __shfl_xor(c, off);
  }

  int cl = 0;
#pragma unroll
  for (int q = 0; q < 16; q++) cl += (ky[q] > K) ? 1 : 0;
  int pre = cl;
#pragma unroll
  for (int off = 1; off < 64; off <<= 1) {
    int t2 = __shfl_up(pre, off);
    if (lane >= off) pre += t2;
  }
  int o = pre - cl;
  cand[wid][lane] = 0ull;
  cand[wid][64 + lane] = 0ull;
  __syncthreads();
#pragma unroll
  for (int q = 0; q < 16; q++) {
    if (ky[q] > K) {
      unsigned idx = (unsigned)(lane * 4 + (q >> 2) * 256 + (q & 3));
      cand[wid][o++] = ((unsigned long long)ky[q] << 32) | (unsigned)(~idx);
    }
  }
  __syncthreads();
  unsigned long long s0 = cand[wid][lane];
  unsigned long long s1 = cand[wid][64 + lane];

#pragma unroll
  for (int k2 = 2; k2 <= 128; k2 <<= 1) {
#pragma unroll
    for (int j = k2 >> 1; j > 0; j >>= 1) {
      if (j == 64) {
        unsigned long long mx = (s0 > s1) ? s0 : s1;
        unsigned long long mn = (s0 > s1) ? s1 : s0;
        s0 = mx; s1 = mn;
      } else {
        bool lower = ((lane & j) == 0);
        bool d0 = ((lane & k2) == 0);
        bool d1 = (((64 + lane) & k2) == 0);
        unsigned long long q0 = shflx64(s0, j);
        unsigned long long q1 = shflx64(s1, j);
        bool kmax0 = (lower == d0);
        bool kmax1 = (lower == d1);
        s0 = (kmax0 == (s0 > q0)) ? s0 : q0;
        s1 = (kmax1 == (s1 > q1)) ? s1 : q1;
      }
    }
  }

  int nval = (c < 40) ? c : 40;
  float pv = 0.f;
  if (lane < nval) pv = __expf(k2f((unsigned)(s0 >> 32)) - m);
  float z10 = (lane < 10) ? pv : 0.f;
  float z20 = (lane < 20) ? pv : 0.f;
  float z40 = pv;
#pragma unroll
  for (int off = 32; off; off >>= 1) {
    z10 += __shfl_xor(z10, off);
    z20 += __shfl_xor(z20, off);
    z40 += __shfl_xor(z40, off);
  }

  float T[3], wcut[3], iZ[3];
  const int kk3[3] = {10, 20, 40};
#pragma unroll
  for (int s3 = 0; s3 < 3; s3++) {
    int k = kk3[s3];
    if (!special || k <= c) {
      unsigned long long sk = shfl64get(s0, k - 1);
      T[s3] = k2f((unsigned)(sk >> 32));
      wcut[s3] = (float)(~(unsigned)sk);
      float Zk = (s3 == 0) ? z10 : ((s3 == 1) ? z20 : z40);
      iZ[s3] = 1.f / Zk;
    } else {
      int r = k - c;
      float vt = k2f(K);
      T[s3] = vt;
      int lo2 = -1, hi2 = 1023;
      while (hi2 - lo2 > 1) {
        int mid = (lo2 + hi2) >> 1;
        int cnt = 0;
#pragma unroll
        for (int q = 0; q < 16; q++) {
          int idx = lane * 4 + (q >> 2) * 256 + (q & 3);
          cnt += (ky[q] == K && idx <= mid) ? 1 : 0;
        }
#pragma unroll
        for (int off = 32; off; off >>= 1) cnt += __shfl_xor(cnt, off);
        if (cnt >= r) hi2 = mid; else lo2 = mid;
      }
      wcut[s3] = (float)hi2;
      iZ[s3] = 1.f / (z40 + (float)r * __expf(vt - m));
    }
  }

  if (lane == 0) {
    float* sp = stats + (size_t)row * 12;
    float4 w0v = {m, 1.f / zf, T[0], T[1]};
    float4 w1v = {T[2], iZ[0], iZ[1], iZ[2]};
    float4 w2v = {wcut[0], wcut[1], wcut[2], 0.f};
    *(float4*)(sp + 0) = w0v;
    *(float4*)(sp + 4) = w1v;
    *(float4*)(sp + 8) = w2v;
  }
}

// ---------------------------------------------------------------------------
// k_init: out[n,o,w,l] = cb[o] + sum_c D[o,c] * x[n,c,w,l]   (fp32 direct path)
__global__ __launch_bounds__(256) void k_init(const float* __restrict__ x,
                                              const float* __restrict__ D,
                                              const float* __restrict__ cb,
                                              float* __restrict__ out) {
  int b = blockIdx.x;
  int n = b >> 10, w = b & 1023;
  int t = threadIdx.x;
  __shared__ float xs[768];
  __shared__ float Ds[64 * 65];
  __shared__ float cbs[64];
  const float* xb = x + (size_t)n * 786432 + w * 12;
  for (int u = t; u < 768; u += 256) {
    int c = u / 12, l2 = u - c * 12;
    xs[u] = xb[(size_t)c * 12288 + l2];
  }
  for (int u = t; u < 4096; u += 256) Ds[(u >> 6) * 65 + (u & 63)] = D[u];
  if (t < 64) cbs[t] = cb[t];
  __syncthreads();
  float* ob = out + (size_t)n * 786432 + w * 12;
  for (int u = t; u < 768; u += 256) {
    int o = u / 12, l2 = u - o * 12;
    float accv = cbs[o];
    const float* dr = &Ds[o * 65];
#pragma unroll
    for (int c = 0; c < 64; c++) accv += dr[c] * xs[c * 12 + l2];
    ob[(size_t)o * 12288 + l2] = accv;
  }
}

// ---------------------------------------------------------------------------
// k_ybuild v2: one block per (nc, mt); x-slice staged ONCE, A-fragments held
// in registers across the nt loop (x reads and f2h work cut 6x). Per nt:
// stage Gt tile via gld16, MFMA, reorder, coalesced store.
__global__ __launch_bounds__(256) void k_ybuild(const float* __restrict__ x,
                                                const unsigned short* __restrict__ Gt,
                                                unsigned short* __restrict__ Y,
                                                int s) {
  int b = blockIdx.x;
  int nc = b / 96;
  int mt = b - nc * 96;
  int n = s + nc;
  int l = mt >> 3;
  int v0 = (mt & 7) << 7;

  __shared__ __align__(16) char smem[34816];
  unsigned short* A2 = (unsigned short*)smem;   // [2][128][32] flat, 16KB
  unsigned short* B2 = (unsigned short*)smem;   // [2][128][32] flat, 16KB (reuse)
  unsigned short(*R)[136] = (unsigned short(*)[136])smem;  // 34816B (reuse)

  int t = threadIdx.x;
  int lane = t & 63, wid = t >> 6;
  int wm = (wid >> 1) * 64, wn = (wid & 1) * 64;
  int ko = (lane >> 4) * 8;
  int mrow = lane & 15;

  // stage A: x[n][c][v0+mloc][l] for c in [half*32, half*32+32)
  {
    int mloc = t >> 1, half = t & 1;
    const float* xp = x + (size_t)n * 786432 + (size_t)(half * 32) * 12288 + (size_t)(v0 + mloc) * 12 + l;
#pragma unroll
    for (int sg = 0; sg < 4; sg++) {
      unsigned q0 = f2h(xp[(size_t)(sg * 8 + 0) * 12288]) | ((unsigned)f2h(xp[(size_t)(sg * 8 + 1) * 12288]) << 16);
      unsigned q1 = f2h(xp[(size_t)(sg * 8 + 2) * 12288]) | ((unsigned)f2h(xp[(size_t)(sg * 8 + 3) * 12288]) << 16);
      unsigned q2 = f2h(xp[(size_t)(sg * 8 + 4) * 12288]) | ((unsigned)f2h(xp[(size_t)(sg * 8 + 5) * 12288]) << 16);
      unsigned q3 = f2h(xp[(size_t)(sg * 8 + 6) * 12288]) | ((unsigned)f2h(xp[(size_t)(sg * 8 + 7) * 12288]) << 16);
      uint4 q = {q0, q1, q2, q3};
      *(uint4*)&A2[(size_t)half * 4096 + (size_t)mloc * 32 + sg * 8] = q;
    }
  }
  __syncthreads();

  // hoist this wave's A-fragments to registers (valid for all nt)
  f16x8 af[2][4];
#pragma unroll
  for (int half = 0; half < 2; half++)
#pragma unroll
    for (int fm = 0; fm < 4; fm++)
      af[half][fm] = *(const f16x8*)(A2 + half * 4096 + (wm + fm * 16 + mrow) * 32 + ko);
  __syncthreads();  // lgkm drained by the implicit waitcnt; A2 region now free

  // per-thread gld16 source decomposition for B2 chunks d = t + 256*i
  const unsigned short* gG[4];
#pragma unroll
  for (int i = 0; i < 4; i++) {
    int d = t + 256 * i;
    int half = d >> 9, row = (d >> 2) & 127, sg = d & 3;
    gG[i] = Gt + (size_t)row * 64 + half * 32 + sg * 8;
  }

  for (int nt = 0; nt < 6; nt++) {
    // stage B2: Gt rows nt*128..+128 (column-major halves), linear LDS dest
#pragma unroll
    for (int i = 0; i < 4; i++)
      gld16(gG[i] + (size_t)nt * 8192, smem + ((size_t)t + 256 * i) * 16);
    __syncthreads();  // drains vmcnt(0): B2 resident

    f32x4 acc[4][4];
#pragma unroll
    for (int fm = 0; fm < 4; fm++)
#pragma unroll
      for (int fn = 0; fn < 4; fn++) acc[fm][fn] = (f32x4){0.f, 0.f, 0.f, 0.f};

#pragma unroll
    for (int half = 0; half < 2; half++) {
      f16x8 bfr[4];
#pragma unroll
      for (int fn = 0; fn < 4; fn++)
        bfr[fn] = *(const f16x8*)(B2 + half * 4096 + (wn + fn * 16 + mrow) * 32 + ko);
#pragma unroll
      for (int fm = 0; fm < 4; fm++)
#pragma unroll
        for (int fn = 0; fn < 4; fn++)
          acc[fm][fn] = __builtin_amdgcn_mfma_f32_16x16x32_f16(af[half][fm], bfr[fn], acc[fm][fn], 0, 0, 0);
    }
    __syncthreads();  // B2 dead; R may overwrite

    // reorder into R[col][m] (m = v offset), 4 consecutive rows per frag-reg
#pragma unroll
    for (int fm = 0; fm < 4; fm++)
#pragma unroll
      for (int fn = 0; fn < 4; fn++) {
        int col = wn + fn * 16 + mrow;
        int mr = wm + fm * 16 + (lane >> 4) * 4;
        unsigned lo = (unsigned)f2h(acc[fm][fn][0]) | ((unsigned)f2h(acc[fm][fn][1]) << 16);
        unsigned hi = (unsigned)f2h(acc[fm][fn][2]) | ((unsigned)f2h(acc[fm][fn][3]) << 16);
        uint2 pk = {lo, hi};
        *(uint2*)&R[col][mr] = pk;
      }
    __syncthreads();

    // coalesced output: row = ncol-local, 128 v contiguous
    {
      int row = t >> 1, hseg = t & 1;
      int ncol = nt * 128 + row;
      int ig = ncol >> 6, o = ncol & 63;
      size_t gbase = ((size_t)nc * 768 + (size_t)(o * 12 + l)) * 12288 + (size_t)ig * 1024 + v0 + hseg * 64;
#pragma unroll
      for (int sg = 0; sg < 8; sg++)
        *(uint4*)(Y + gbase + sg * 8) = *(const uint4*)&R[row][hseg * 64 + sg * 8];
    }
    __syncthreads();  // all R reads done before next nt's B2 stage
  }
}

// ---------------------------------------------------------------------------
// k_buildA: A[(nc*1024+w)*12288 + i*4096 + g*1024 + v] = fp16 softmax weights
__global__ __launch_bounds__(256) void k_buildA(const float* __restrict__ support,
                                                const float* __restrict__ stats,
                                                unsigned short* __restrict__ Abuf,
                                                int s) {
  int b = blockIdx.x;
  int nc = b / 3072;
  int rem2 = b - nc * 3072;
  int i = rem2 >> 10;
  int tile = rem2 & 1023;
  int v0 = (tile >> 5) << 5;
  int w0 = (tile & 31) << 5;
  int n = s + nc;
  const float* sup = support + (size_t)(n * 3 + i) * 1024 * 1024;
  const float* stb = stats + (size_t)(n * 3 + i) * 1024 * 12;

  __shared__ float S[32][33];
  __shared__ float st[32][12];
  int t = threadIdx.x;
  {
    int vl = t >> 3, wseg = t & 7;
    const float* p = sup + (size_t)(v0 + vl) * 1024 + w0 + wseg * 4;
    float4 f = *(const float4*)p;
    S[vl][wseg * 4 + 0] = f.x;
    S[vl][wseg * 4 + 1] = f.y;
    S[vl][wseg * 4 + 2] = f.z;
    S[vl][wseg * 4 + 3] = f.w;
  }
  for (int u = t; u < 384; u += 256) {
    int vl = u / 12, q = u - vl * 12;
    st[vl][q] = stb[(size_t)(v0 + vl) * 12 + q];
  }
  __syncthreads();

  int w_loc = t >> 3, vseg = t & 7;
  float wg = (float)(w0 + w_loc);
  unsigned short bv[4][4];
#pragma unroll
  for (int j = 0; j < 4; j++) {
    int vl = vseg * 4 + j;
    float aa = S[vl][w_loc];
    float m = st[vl][0], izf = st[vl][1];
    float T10 = st[vl][2], T20 = st[vl][3], T40 = st[vl][4];
    float iz10 = st[vl][5], iz20 = st[vl][6], iz40 = st[vl][7];
    float w10 = st[vl][8], w20 = st[vl][9], w40 = st[vl][10];
    float ee = __expf(aa - m);
    bool in10 = (aa > T10) || (aa == T10 && wg <= w10);
    bool in20 = (aa > T20) || (aa == T20 && wg <= w20);
    bool in40 = (aa > T40) || (aa == T40 && wg <= w40);
    bv[3][j] = f2h(ee * izf);
    bv[2][j] = f2h(in40 ? ee * iz40 : 0.f);
    bv[1][j] = f2h(in20 ? ee * iz20 : 0.f);
    bv[0][j] = f2h(in10 ? ee * iz10 : 0.f);
  }
  size_t base = ((size_t)nc * 1024 + w0 + w_loc) * 12288 + (size_t)i * 4096 + v0 + vseg * 4;
#pragma unroll
  for (int g = 0; g < 4; g++) {
    uint2 pk;
    pk.x = (unsigned)bv[g][0] | ((unsigned)bv[g][1] << 16);
    pk.y = (unsigned)bv[g][2] | ((unsigned)bv[g][3] << 16);
    *(uint2*)(Abuf + base + (size_t)g * 1024) = pk;
  }
}

// ---------------------------------------------------------------------------
// k_biggemm v6: round-2 skeleton (proven best: gld16 direct staging, 2
// barriers per K-step) with BK=64: each step stages 32KB (8 gld16/thread) and
// runs 32 MFMA/wave, halving the per-step drain+barrier overhead count.
// [128][64] fp16 rows would be a 16-way bank conflict, so apply the r3-proven
// chunk-rotation swizzle: physical 16B-chunk (q + row&7)&7, realized as
// inverse-permuted GLOBAL source (within-row => coalescing intact) + permuted
// ds_read offset. MFMA K-order identical to v2 (bit-identical output).
__global__ __launch_bounds__(256) void k_biggemm(const unsigned short* __restrict__ A,
                                                 const unsigned short* __restrict__ Y,
                                                 float* __restrict__ out,
                                                 int s) {
  // XCD swizzle: grid = Cc*48, always % 8 == 0 -> simple bijective remap.
  int b = blockIdx.x;
  int cpx = gridDim.x >> 3;
  b = (b & 7) * cpx + (b >> 3);

  int nc = b / 48;
  int rem2 = b - nc * 48;
  int mt = rem2 / 6, nt = rem2 - (rem2 / 6) * 6;
  int n = s + nc;

  // [128 rows][64 elems] per tensor, fp16. 32 KB total; 3 blocks/CU = 96 KB.
  __shared__ __align__(16) unsigned short SA[128 * 64];
  __shared__ __align__(16) unsigned short SB[128 * 64];

  int t = threadIdx.x;
  int lane = t & 63, wid = t >> 6;
  int wm = (wid >> 1) * 64, wn = (wid & 1) * 64;

  const unsigned short* Ab = A + (size_t)nc * 12582912 + (size_t)(mt * 128) * 12288;
  const unsigned short* Yb = Y + (size_t)nc * 9437184 + (size_t)(nt * 128) * 12288;

  // Staging: LDS chunk d = t + 256*i (i=0..3), linear dest byte d*16.
  // d -> row = d>>3, dcol = d&7. Source holds logical chunk
  // c = (dcol - (row&7)) & 7 of that row (within the row's 128B line).
  const unsigned short* gA[4];
  const unsigned short* gB[4];
#pragma unroll
  for (int i = 0; i < 4; i++) {
    int d = t + 256 * i;
    int row = d >> 3, dcol = d & 7;
    int c = (dcol - (row & 7)) & 7;
    gA[i] = Ab + (size_t)row * 12288 + c * 8;
    gB[i] = Yb + (size_t)row * 12288 + c * 8;
  }

  f32x4 acc[4][4];
#pragma unroll
  for (int fm = 0; fm < 4; fm++)
#pragma unroll
    for (int fn = 0; fn < 4; fn++) acc[fm][fn] = (f32x4){0.f, 0.f, 0.f, 0.f};

  int mrow = lane & 15;
  // Read: logical chunk q = ks*4 + (lane>>4); physical = (q + row&7)&7 with
  // row&7 = lane&7 (wm/fm*16 are multiples of 16 -> drop mod 8... row&7 =
  // (mrow)&7 = lane&7). Element offset = physical*8.
  int cp0 = ((((lane >> 4) + (lane & 7)) & 7)) * 8;      // ks = 0
  int cp1 = ((((lane >> 4) + 4 + (lane & 7)) & 7)) * 8;  // ks = 1

  for (int kt = 0; kt < 192; kt++) {
    __syncthreads();  // previous step's ds_reads done before DMA overwrites LDS
#pragma unroll
    for (int i = 0; i < 4; i++) {
      gld16(gA[i], (char*)SA + ((size_t)t + 256 * i) * 16);
      gld16(gB[i], (char*)SB + ((size_t)t + 256 * i) * 16);
      gA[i] += 64;
      gB[i] += 64;
    }
    __syncthreads();  // vmcnt(0) drain before s_barrier -> tile ready
#pragma unroll
    for (int ks = 0; ks < 2; ks++) {
      int cpo = ks ? cp1 : cp0;
      f16x8 af[4], bfr[4];
#pragma unroll
      for (int fm = 0; fm < 4; fm++)
        af[fm] = *(const f16x8*)&SA[(wm + fm * 16 + mrow) * 64 + cpo];
#pragma unroll
      for (int fn = 0; fn < 4; fn++)
        bfr[fn] = *(const f16x8*)&SB[(wn + fn * 16 + mrow) * 64 + cpo];
#pragma unroll
      for (int fm = 0; fm < 4; fm++)
#pragma unroll
        for (int fn = 0; fn < 4; fn++)
          acc[fm][fn] = __builtin_amdgcn_mfma_f32_16x16x32_f16(af[fm], bfr[fn], acc[fm][fn], 0, 0, 0);
    }
  }

  // epilogue: RMW into out (tiles are exclusive)
  float* ob = out + (size_t)n * 786432;
#pragma unroll
  for (int fn = 0; fn < 4; fn++) {
    int col = nt * 128 + wn + fn * 16 + (lane & 15);  // = o*12 + l
    int oo = col / 12;
    int ll2 = col - oo * 12;
    float* cbase = ob + (size_t)oo * 12288 + ll2;
#pragma unroll
    for (int fm = 0; fm < 4; fm++) {
      int w = mt * 128 + wm + fm * 16 + (lane >> 4) * 4;
      float* p = cbase + (size_t)w * 12;
#pragma unroll
      for (int r = 0; r < 4; r++) p[r * 12] += acc[fm][fn][r];
    }
  }
}

// ---------------------------------------------------------------------------
extern "C" void kernel_launch(void* const* d_in, const int* in_sizes, int n_in,
                              void* d_out, int out_size, void* d_ws, size_t ws_size,
                              hipStream_t stream) {
  const float* x = (const float*)d_in[0];
  const float* support = (const float*)d_in[1];
  const float* W0 = (const float*)d_in[2];
  const float* b0 = (const float*)d_in[3];
  const float* Ws = (const float*)d_in[4];
  const float* bs = (const float*)d_in[5];
  const float* Wf = (const float*)d_in[6];
  const float* bf = (const float*)d_in[7];
  float* out = (float*)d_out;
  char* ws = (char*)d_ws;

  float* stats = (float*)ws;                              // 49152*12*4 = 2,359,296 B
  float* D = (float*)(ws + 2359296);                      // 16,384 B
  float* cb = (float*)(ws + 2375680);                     // 256 B
  unsigned short* Gt = (unsigned short*)(ws + 2375936);   // 98,304 B
  const size_t fixed_end = 2474240;
  const size_t szY = 18874368;  // per n
  const size_t szA = 25165824;  // per n

  int C = 1;
  if (ws_size > fixed_end) {
    size_t remb = ws_size - fixed_end;
    size_t c = remb / (szY + szA);
    if (c > 16) c = 16;
    if (c < 1) c = 1;
    C = (int)c;
  }
  unsigned short* Ybuf = (unsigned short*)(ws + fixed_end);
  unsigned short* Abuf = (unsigned short*)(ws + fixed_end + (size_t)C * szY);

  k_prep<<<13, 256, 0, stream>>>(W0, b0, Ws, bs, Wf, bf, D, cb, Gt);
  k_stats<<<12288, 256, 0, stream>>>(support, stats);
  k_init<<<16384, 256, 0, stream>>>(x, D, cb, out);
  for (int s = 0; s < 16; s += C) {
    int Cc = (16 - s) < C ? (16 - s) : C;
    k_ybuild<<<Cc * 96, 256, 0, stream>>>(x, Gt, Ybuf, s);
    k_buildA<<<Cc * 3072, 256, 0, stream>>>(support, stats, Abuf, s);
    k_biggemm<<<Cc * 48, 256, 0, stream>>>(Abuf, Ybuf, out, s);
  }
}

// Round 7
// 1133.824 us; speedup vs baseline: 1.1320x; 1.1320x over previous
//
#include <hip/hip_runtime.h>
#include <hip/hip_bf16.h>
#include <hip/hip_fp16.h>

// Problem constants
// x: (16,64,1024,12) f32, support: (16,3,1024,1024) f32
// out: (16,64,1024,12) f32
#define NB 16
#define V 1024
#define LL 12
#define C64 64
#define SL 3
#define CL 768        // 64*12
#define KTOT 12288    // 12*1024
#define MARKOFF -1e20f

typedef _Float16 f16x8 __attribute__((ext_vector_type(8)));
typedef __attribute__((ext_vector_type(4))) float f32x4;

// fp32 -> fp16 bits (RN). All quantized tensors (x, G, Y, A) are
// small-magnitude; fp16 gives 8x lower rounding error than bf16 at the same
// MFMA rate.
static __device__ __forceinline__ unsigned short f2h(float f) {
  __half h = __float2half(f);
  return __builtin_bit_cast(unsigned short, h);
}

// async global->LDS direct staging, 16B per lane.
// LDS dest must be wave-uniform base + lane*16 (it is: byte offset = t*16).
typedef const __attribute__((address_space(1))) unsigned int gas_u32;
typedef __attribute__((address_space(3))) unsigned int las_u32;
static __device__ __forceinline__ void gld16(const void* g, void* l) {
  __builtin_amdgcn_global_load_lds((gas_u32*)g, (las_u32*)l, 16, 0, 0);
}

// 64-bit cross-lane helpers (2x32-bit shuffles)
static __device__ __forceinline__ unsigned long long shflx64(unsigned long long v, int m) {
  unsigned lo = __shfl_xor((unsigned)v, m);
  unsigned hi = __shfl_xor((unsigned)(v >> 32), m);
  return ((unsigned long long)hi << 32) | lo;
}
static __device__ __forceinline__ unsigned long long shfl64get(unsigned long long v, int srcLane) {
  unsigned lo = __shfl((unsigned)v, srcLane);
  unsigned hi = __shfl((unsigned)(v >> 32), srcLane);
  return ((unsigned long long)hi << 32) | lo;
}
// monotone key <-> float
static __device__ __forceinline__ float k2f(unsigned kk) {
  unsigned u = (kk & 0x80000000u) ? (kk & 0x7FFFFFFFu) : ~kk;
  return __uint_as_float(u);
}

// ---------------------------------------------------------------------------
// k_prep: D = F0*W0 (fp32), Gt[(ig*64+o)][c] = fp16( sum_c2 Wf[o,64(i+1)+c2]*Ws[i][c2][64g+c] ),
//         cb[o] = bf[o] + F0*b0 + sum_i F_{i+1}*bs[i]
__global__ __launch_bounds__(256) void k_prep(const float* __restrict__ W0,
                                              const float* __restrict__ b0,
                                              const float* __restrict__ Ws,
                                              const float* __restrict__ bs,
                                              const float* __restrict__ Wf,
                                              const float* __restrict__ bf,
                                              float* __restrict__ D,
                                              float* __restrict__ cb,
                                              unsigned short* __restrict__ Gt) {
  int b = blockIdx.x;
  int t = threadIdx.x;
  int o = t >> 2, cp = t & 3;
  if (b < 12) {
    int i = b >> 2, g = b & 3;
    for (int c = cp * 16; c < cp * 16 + 16; c++) {
      float acc = 0.f;
      for (int c2 = 0; c2 < 64; c2++)
        acc += Wf[o * 256 + 64 * (i + 1) + c2] * Ws[i * 16384 + c2 * 256 + g * 64 + c];
      Gt[(size_t)(b * 64 + o) * 64 + c] = f2h(acc);
    }
  } else {
    for (int c = cp * 16; c < cp * 16 + 16; c++) {
      float acc = 0.f;
      for (int c2 = 0; c2 < 64; c2++)
        acc += Wf[o * 256 + c2] * W0[c2 * 64 + c];
      D[o * 64 + c] = acc;
    }
    if (t < 64) {
      float acc = bf[t];
      for (int c2 = 0; c2 < 64; c2++) acc += Wf[t * 256 + c2] * b0[c2];
      for (int i = 0; i < 3; i++)
        for (int c2 = 0; c2 < 64; c2++) acc += Wf[t * 256 + 64 * (i + 1) + c2] * bs[i * 64 + c2];
      cb[t] = acc;
    }
  }
}

// ---------------------------------------------------------------------------
// k_stats v2: ONE WAVE PER ROW, barrier-light, atomic-free, histogram-free.
__global__ __launch_bounds__(256) void k_stats(const float* __restrict__ support,
                                               float* __restrict__ stats) {
  int t = threadIdx.x;
  int lane = t & 63, wid = t >> 6;
  int row = blockIdx.x * 4 + wid;  // (n*3+i)*1024 + v
  const float* a = support + (size_t)row * 1024;

  __shared__ unsigned long long cand[4][128];

  float va[16];
  const float4* a4 = (const float4*)a;
#pragma unroll
  for (int j = 0; j < 4; j++) {
    float4 f = a4[lane + 64 * j];
    va[j * 4 + 0] = f.x; va[j * 4 + 1] = f.y; va[j * 4 + 2] = f.z; va[j * 4 + 3] = f.w;
  }

  float m = va[0];
#pragma unroll
  for (int q = 1; q < 16; q++) m = fmaxf(m, va[q]);
#pragma unroll
  for (int off = 32; off; off >>= 1) m = fmaxf(m, __shfl_xor(m, off));

  float zf = 0.f;
#pragma unroll
  for (int q = 0; q < 16; q++) zf += __expf(va[q] - m);
#pragma unroll
  for (int off = 32; off; off >>= 1) zf += __shfl_xor(zf, off);

  unsigned ky[16];
#pragma unroll
  for (int q = 0; q < 16; q++) {
    unsigned u = __float_as_uint(va[q]);
    ky[q] = (u & 0x80000000u) ? ~u : (u | 0x80000000u);
  }

  unsigned Klo = 0u, Khi = 0xFFFFFFFFu;
  unsigned K = 0xBFB33333u;  // key(1.4f) seed
  int c = 0;
  bool ok = false;
  for (int it = 0; it < 40; ++it) {
    int cl = 0;
#pragma unroll
    for (int q = 0; q < 16; q++) cl += (ky[q] > K) ? 1 : 0;
    c = cl;
#pragma unroll
    for (int off = 32; off; off >>= 1) c += __shfl_xor(c, off);
    if (c >= 40 && c <= 128) { ok = true; break; }
    if (c > 128) Klo = K; else Khi = K;
    if (Khi - Klo <= 1u) break;
    K = Klo + ((Khi - Klo) >> 1);
  }
  bool special = !ok;
  if (special) {
    K = Khi;
    int cl = 0;
#pragma unroll
    for (int q = 0; q < 16; q++) cl += (ky[q] > K) ? 1 : 0;
    c = cl;
#pragma unroll
    for (int off = 32; off; off >>= 1) c += __shfl_xor(c, off);
  }

  int cl = 0;
#pragma unroll
  for (int q = 0; q < 16; q++) cl += (ky[q] > K) ? 1 : 0;
  int pre = cl;
#pragma unroll
  for (int off = 1; off < 64; off <<= 1) {
    int t2 = __shfl_up(pre, off);
    if (lane >= off) pre += t2;
  }
  int o = pre - cl;
  cand[wid][lane] = 0ull;
  cand[wid][64 + lane] = 0ull;
  __syncthreads();
#pragma unroll
  for (int q = 0; q < 16; q++) {
    if (ky[q] > K) {
      unsigned idx = (unsigned)(lane * 4 + (q >> 2) * 256 + (q & 3));
      cand[wid][o++] = ((unsigned long long)ky[q] << 32) | (unsigned)(~idx);
    }
  }
  __syncthreads();
  unsigned long long s0 = cand[wid][lane];
  unsigned long long s1 = cand[wid][64 + lane];

#pragma unroll
  for (int k2 = 2; k2 <= 128; k2 <<= 1) {
#pragma unroll
    for (int j = k2 >> 1; j > 0; j >>= 1) {
      if (j == 64) {
        unsigned long long mx = (s0 > s1) ? s0 : s1;
        unsigned long long mn = (s0 > s1) ? s1 : s0;
        s0 = mx; s1 = mn;
      } else {
        bool lower = ((lane & j) == 0);
        bool d0 = ((lane & k2) == 0);
        bool d1 = (((64 + lane) & k2) == 0);
        unsigned long long q0 = shflx64(s0, j);
        unsigned long long q1 = shflx64(s1, j);
        bool kmax0 = (lower == d0);
        bool kmax1 = (lower == d1);
        s0 = (kmax0 == (s0 > q0)) ? s0 : q0;
        s1 = (kmax1 == (s1 > q1)) ? s1 : q1;
      }
    }
  }

  int nval = (c < 40) ? c : 40;
  float pv = 0.f;
  if (lane < nval) pv = __expf(k2f((unsigned)(s0 >> 32)) - m);
  float z10 = (lane < 10) ? pv : 0.f;
  float z20 = (lane < 20) ? pv : 0.f;
  float z40 = pv;
#pragma unroll
  for (int off = 32; off; off >>= 1) {
    z10 += __shfl_xor(z10, off);
    z20 += __shfl_xor(z20, off);
    z40 += __shfl_xor(z40, off);
  }

  float T[3], wcut[3], iZ[3];
  const int kk3[3] = {10, 20, 40};
#pragma unroll
  for (int s3 = 0; s3 < 3; s3++) {
    int k = kk3[s3];
    if (!special || k <= c) {
      unsigned long long sk = shfl64get(s0, k - 1);
      T[s3] = k2f((unsigned)(sk >> 32));
      wcut[s3] = (float)(~(unsigned)sk);
      float Zk = (s3 == 0) ? z10 : ((s3 == 1) ? z20 : z40);
      iZ[s3] = 1.f / Zk;
    } else {
      int r = k - c;
      float vt = k2f(K);
      T[s3] = vt;
      int lo2 = -1, hi2 = 1023;
      while (hi2 - lo2 > 1) {
        int mid = (lo2 + hi2) >> 1;
        int cnt = 0;
#pragma unroll
        for (int q = 0; q < 16; q++) {
          int idx = lane * 4 + (q >> 2) * 256 + (q & 3);
          cnt += (ky[q] == K && idx <= mid) ? 1 : 0;
        }
#pragma unroll
        for (int off = 32; off; off >>= 1) cnt += __shfl_xor(cnt, off);
        if (cnt >= r) hi2 = mid; else lo2 = mid;
      }
      wcut[s3] = (float)hi2;
      iZ[s3] = 1.f / (z40 + (float)r * __expf(vt - m));
    }
  }

  if (lane == 0) {
    float* sp = stats + (size_t)row * 12;
    float4 w0v = {m, 1.f / zf, T[0], T[1]};
    float4 w1v = {T[2], iZ[0], iZ[1], iZ[2]};
    float4 w2v = {wcut[0], wcut[1], wcut[2], 0.f};
    *(float4*)(sp + 0) = w0v;
    *(float4*)(sp + 4) = w1v;
    *(float4*)(sp + 8) = w2v;
  }
}

// ---------------------------------------------------------------------------
// k_init: out[n,o,w,l] = cb[o] + sum_c D[o,c] * x[n,c,w,l]   (fp32 direct path)
__global__ __launch_bounds__(256) void k_init(const float* __restrict__ x,
                                              const float* __restrict__ D,
                                              const float* __restrict__ cb,
                                              float* __restrict__ out) {
  int b = blockIdx.x;
  int n = b >> 10, w = b & 1023;
  int t = threadIdx.x;
  __shared__ float xs[768];
  __shared__ float Ds[64 * 65];
  __shared__ float cbs[64];
  const float* xb = x + (size_t)n * 786432 + w * 12;
  for (int u = t; u < 768; u += 256) {
    int c = u / 12, l2 = u - c * 12;
    xs[u] = xb[(size_t)c * 12288 + l2];
  }
  for (int u = t; u < 4096; u += 256) Ds[(u >> 6) * 65 + (u & 63)] = D[u];
  if (t < 64) cbs[t] = cb[t];
  __syncthreads();
  float* ob = out + (size_t)n * 786432 + w * 12;
  for (int u = t; u < 768; u += 256) {
    int o = u / 12, l2 = u - o * 12;
    float accv = cbs[o];
    const float* dr = &Ds[o * 65];
#pragma unroll
    for (int c = 0; c < 64; c++) accv += dr[c] * xs[c * 12 + l2];
    ob[(size_t)o * 12288 + l2] = accv;
  }
}

// ---------------------------------------------------------------------------
// k_ybuild v2: one block per (nc, mt); x-slice staged ONCE, A-fragments held
// in registers across the nt loop (x reads and f2h work cut 6x). Per nt:
// stage Gt tile via gld16, MFMA, reorder, coalesced store.
__global__ __launch_bounds__(256) void k_ybuild(const float* __restrict__ x,
                                                const unsigned short* __restrict__ Gt,
                                                unsigned short* __restrict__ Y,
                                                int s) {
  int b = blockIdx.x;
  int nc = b / 96;
  int mt = b - nc * 96;
  int n = s + nc;
  int l = mt >> 3;
  int v0 = (mt & 7) << 7;

  __shared__ __align__(16) char smem[34816];
  unsigned short* A2 = (unsigned short*)smem;   // [2][128][32] flat, 16KB
  unsigned short* B2 = (unsigned short*)smem;   // [2][128][32] flat, 16KB (reuse)
  unsigned short(*R)[136] = (unsigned short(*)[136])smem;  // 34816B (reuse)

  int t = threadIdx.x;
  int lane = t & 63, wid = t >> 6;
  int wm = (wid >> 1) * 64, wn = (wid & 1) * 64;
  int ko = (lane >> 4) * 8;
  int mrow = lane & 15;

  // stage A: x[n][c][v0+mloc][l] for c in [half*32, half*32+32)
  {
    int mloc = t >> 1, half = t & 1;
    const float* xp = x + (size_t)n * 786432 + (size_t)(half * 32) * 12288 + (size_t)(v0 + mloc) * 12 + l;
#pragma unroll
    for (int sg = 0; sg < 4; sg++) {
      unsigned q0 = f2h(xp[(size_t)(sg * 8 + 0) * 12288]) | ((unsigned)f2h(xp[(size_t)(sg * 8 + 1) * 12288]) << 16);
      unsigned q1 = f2h(xp[(size_t)(sg * 8 + 2) * 12288]) | ((unsigned)f2h(xp[(size_t)(sg * 8 + 3) * 12288]) << 16);
      unsigned q2 = f2h(xp[(size_t)(sg * 8 + 4) * 12288]) | ((unsigned)f2h(xp[(size_t)(sg * 8 + 5) * 12288]) << 16);
      unsigned q3 = f2h(xp[(size_t)(sg * 8 + 6) * 12288]) | ((unsigned)f2h(xp[(size_t)(sg * 8 + 7) * 12288]) << 16);
      uint4 q = {q0, q1, q2, q3};
      *(uint4*)&A2[(size_t)half * 4096 + (size_t)mloc * 32 + sg * 8] = q;
    }
  }
  __syncthreads();

  // hoist this wave's A-fragments to registers (valid for all nt)
  f16x8 af[2][4];
#pragma unroll
  for (int half = 0; half < 2; half++)
#pragma unroll
    for (int fm = 0; fm < 4; fm++)
      af[half][fm] = *(const f16x8*)(A2 + half * 4096 + (wm + fm * 16 + mrow) * 32 + ko);
  __syncthreads();  // lgkm drained by the implicit waitcnt; A2 region now free

  // per-thread gld16 source decomposition for B2 chunks d = t + 256*i
  const unsigned short* gG[4];
#pragma unroll
  for (int i = 0; i < 4; i++) {
    int d = t + 256 * i;
    int half = d >> 9, row = (d >> 2) & 127, sg = d & 3;
    gG[i] = Gt + (size_t)row * 64 + half * 32 + sg * 8;
  }

  for (int nt = 0; nt < 6; nt++) {
    // stage B2: Gt rows nt*128..+128 (column-major halves), linear LDS dest
#pragma unroll
    for (int i = 0; i < 4; i++)
      gld16(gG[i] + (size_t)nt * 8192, smem + ((size_t)t + 256 * i) * 16);
    __syncthreads();  // drains vmcnt(0): B2 resident

    f32x4 acc[4][4];
#pragma unroll
    for (int fm = 0; fm < 4; fm++)
#pragma unroll
      for (int fn = 0; fn < 4; fn++) acc[fm][fn] = (f32x4){0.f, 0.f, 0.f, 0.f};

#pragma unroll
    for (int half = 0; half < 2; half++) {
      f16x8 bfr[4];
#pragma unroll
      for (int fn = 0; fn < 4; fn++)
        bfr[fn] = *(const f16x8*)(B2 + half * 4096 + (wn + fn * 16 + mrow) * 32 + ko);
#pragma unroll
      for (int fm = 0; fm < 4; fm++)
#pragma unroll
        for (int fn = 0; fn < 4; fn++)
          acc[fm][fn] = __builtin_amdgcn_mfma_f32_16x16x32_f16(af[half][fm], bfr[fn], acc[fm][fn], 0, 0, 0);
    }
    __syncthreads();  // B2 dead; R may overwrite

    // reorder into R[col][m] (m = v offset), 4 consecutive rows per frag-reg
#pragma unroll
    for (int fm = 0; fm < 4; fm++)
#pragma unroll
      for (int fn = 0; fn < 4; fn++) {
        int col = wn + fn * 16 + mrow;
        int mr = wm + fm * 16 + (lane >> 4) * 4;
        unsigned lo = (unsigned)f2h(acc[fm][fn][0]) | ((unsigned)f2h(acc[fm][fn][1]) << 16);
        unsigned hi = (unsigned)f2h(acc[fm][fn][2]) | ((unsigned)f2h(acc[fm][fn][3]) << 16);
        uint2 pk = {lo, hi};
        *(uint2*)&R[col][mr] = pk;
      }
    __syncthreads();

    // coalesced output: row = ncol-local, 128 v contiguous
    {
      int row = t >> 1, hseg = t & 1;
      int ncol = nt * 128 + row;
      int ig = ncol >> 6, o = ncol & 63;
      size_t gbase = ((size_t)nc * 768 + (size_t)(o * 12 + l)) * 12288 + (size_t)ig * 1024 + v0 + hseg * 64;
#pragma unroll
      for (int sg = 0; sg < 8; sg++)
        *(uint4*)(Y + gbase + sg * 8) = *(const uint4*)&R[row][hseg * 64 + sg * 8];
    }
    __syncthreads();  // all R reads done before next nt's B2 stage
  }
}

// ---------------------------------------------------------------------------
// k_buildA: A[(nc*1024+w)*12288 + i*4096 + g*1024 + v] = fp16 softmax weights
__global__ __launch_bounds__(256) void k_buildA(const float* __restrict__ support,
                                                const float* __restrict__ stats,
                                                unsigned short* __restrict__ Abuf,
                                                int s) {
  int b = blockIdx.x;
  int nc = b / 3072;
  int rem2 = b - nc * 3072;
  int i = rem2 >> 10;
  int tile = rem2 & 1023;
  int v0 = (tile >> 5) << 5;
  int w0 = (tile & 31) << 5;
  int n = s + nc;
  const float* sup = support + (size_t)(n * 3 + i) * 1024 * 1024;
  const float* stb = stats + (size_t)(n * 3 + i) * 1024 * 12;

  __shared__ float S[32][33];
  __shared__ float st[32][12];
  int t = threadIdx.x;
  {
    int vl = t >> 3, wseg = t & 7;
    const float* p = sup + (size_t)(v0 + vl) * 1024 + w0 + wseg * 4;
    float4 f = *(const float4*)p;
    S[vl][wseg * 4 + 0] = f.x;
    S[vl][wseg * 4 + 1] = f.y;
    S[vl][wseg * 4 + 2] = f.z;
    S[vl][wseg * 4 + 3] = f.w;
  }
  for (int u = t; u < 384; u += 256) {
    int vl = u / 12, q = u - vl * 12;
    st[vl][q] = stb[(size_t)(v0 + vl) * 12 + q];
  }
  __syncthreads();

  int w_loc = t >> 3, vseg = t & 7;
  float wg = (float)(w0 + w_loc);
  unsigned short bv[4][4];
#pragma unroll
  for (int j = 0; j < 4; j++) {
    int vl = vseg * 4 + j;
    float aa = S[vl][w_loc];
    float m = st[vl][0], izf = st[vl][1];
    float T10 = st[vl][2], T20 = st[vl][3], T40 = st[vl][4];
    float iz10 = st[vl][5], iz20 = st[vl][6], iz40 = st[vl][7];
    float w10 = st[vl][8], w20 = st[vl][9], w40 = st[vl][10];
    float ee = __expf(aa - m);
    bool in10 = (aa > T10) || (aa == T10 && wg <= w10);
    bool in20 = (aa > T20) || (aa == T20 && wg <= w20);
    bool in40 = (aa > T40) || (aa == T40 && wg <= w40);
    bv[3][j] = f2h(ee * izf);
    bv[2][j] = f2h(in40 ? ee * iz40 : 0.f);
    bv[1][j] = f2h(in20 ? ee * iz20 : 0.f);
    bv[0][j] = f2h(in10 ? ee * iz10 : 0.f);
  }
  size_t base = ((size_t)nc * 1024 + w0 + w_loc) * 12288 + (size_t)i * 4096 + v0 + vseg * 4;
#pragma unroll
  for (int g = 0; g < 4; g++) {
    uint2 pk;
    pk.x = (unsigned)bv[g][0] | ((unsigned)bv[g][1] << 16);
    pk.y = (unsigned)bv[g][2] | ((unsigned)bv[g][3] << 16);
    *(uint2*)(Abuf + base + (size_t)g * 1024) = pk;
  }
}

// ---------------------------------------------------------------------------
// k_biggemm v7: EXACT round-2 skeleton (128x128, BK=32, 16KB LDS, gld16 direct
// staging, 2 barriers/K-step — empirical best 428us) + ONLY the chunk-rotation
// swizzle, folded entirely into pre-loop setup (zero extra loop instructions).
// Physical 16B-chunk of (row, q) = (q + (row>>1)) & 3, realized as inverse-
// permuted GLOBAL source (within-row => coalescing unchanged) + rotated
// ds_read offset. Single variable vs r2: LDS 8-way read conflicts -> 2-way
// (free). Data entering each MFMA is bit-identical to r2.
__global__ __launch_bounds__(256) void k_biggemm(const unsigned short* __restrict__ A,
                                                 const unsigned short* __restrict__ Y,
                                                 float* __restrict__ out,
                                                 int s) {
  // XCD swizzle: grid = Cc*48, always % 8 == 0 -> simple bijective remap.
  int b = blockIdx.x;
  int cpx = gridDim.x >> 3;
  b = (b & 7) * cpx + (b >> 3);

  int nc = b / 48;
  int rem2 = b - nc * 48;
  int mt = rem2 / 6, nt = rem2 - (rem2 / 6) * 6;
  int n = s + nc;

  __shared__ __align__(16) unsigned short A3[128][32];
  __shared__ __align__(16) unsigned short B3[128][32];

  int t = threadIdx.x;
  int lane = t & 63, wid = t >> 6;
  int wm = (wid >> 1) * 64, wn = (wid & 1) * 64;

  const unsigned short* Ab = A + (size_t)nc * 12582912 + (size_t)(mt * 128) * 12288;
  const unsigned short* Yb = Y + (size_t)nc * 9437184 + (size_t)(nt * 128) * 12288;

  // staging map with inverse rotation: thread t fills LDS chunk d=t (row t>>2,
  // slot t&3) and d=t+256 (row 64+(t>>2), same slot). Rotation key (row>>1)&3
  // = (t>>3)&3 for BOTH (64 rows apart => key identical). Source chunk:
  int srow = t >> 2;
  int scc = ((t & 3) - ((t >> 3) & 3)) & 3;
  const unsigned short* gA0 = Ab + (size_t)srow * 12288 + scc * 8;
  const unsigned short* gA1 = gA0 + (size_t)64 * 12288;
  const unsigned short* gB0 = Yb + (size_t)srow * 12288 + scc * 8;
  const unsigned short* gB1 = gB0 + (size_t)64 * 12288;
  unsigned short* lA0 = &A3[0][0] + (size_t)t * 8;
  unsigned short* lA1 = lA0 + 2048;
  unsigned short* lB0 = &B3[0][0] + (size_t)t * 8;
  unsigned short* lB1 = lB0 + 2048;

  f32x4 acc[4][4];
#pragma unroll
  for (int fm = 0; fm < 4; fm++)
#pragma unroll
    for (int fn = 0; fn < 4; fn++) acc[fm][fn] = (f32x4){0.f, 0.f, 0.f, 0.f};

  // read offset: logical chunk q = lane>>4 of row (..+lane&15); physical slot
  // = (q + ((lane>>1)&3)) & 3 (row>>1 mod 4 == (lane&15)>>1 mod 4).
  int cpo = (((lane >> 4) + ((lane >> 1) & 3)) & 3) * 8;

  for (int kt = 0; kt < 384; kt++) {
    __syncthreads();  // previous step's ds_reads done before DMA overwrites LDS
    gld16(gA0, lA0);
    gld16(gA1, lA1);
    gld16(gB0, lB0);
    gld16(gB1, lB1);
    gA0 += 32; gA1 += 32; gB0 += 32; gB1 += 32;
    __syncthreads();  // vmcnt(0) drain before s_barrier -> tile ready
    f16x8 af[4], bfr[4];
#pragma unroll
    for (int fm = 0; fm < 4; fm++) af[fm] = *(const f16x8*)&A3[wm + fm * 16 + (lane & 15)][cpo];
#pragma unroll
    for (int fn = 0; fn < 4; fn++) bfr[fn] = *(const f16x8*)&B3[wn + fn * 16 + (lane & 15)][cpo];
#pragma unroll
    for (int fm = 0; fm < 4; fm++)
#pragma unroll
      for (int fn = 0; fn < 4; fn++)
        acc[fm][fn] = __builtin_amdgcn_mfma_f32_16x16x32_f16(af[fm], bfr[fn], acc[fm][fn], 0, 0, 0);
  }

  // epilogue: RMW into out (tiles are exclusive)
  float* ob = out + (size_t)n * 786432;
#pragma unroll
  for (int fn = 0; fn < 4; fn++) {
    int col = nt * 128 + wn + fn * 16 + (lane & 15);  // = o*12 + l
    int oo = col / 12;
    int ll2 = col - oo * 12;
    float* cbase = ob + (size_t)oo * 12288 + ll2;
#pragma unroll
    for (int fm = 0; fm < 4; fm++) {
      int w = mt * 128 + wm + fm * 16 + (lane >> 4) * 4;
      float* p = cbase + (size_t)w * 12;
#pragma unroll
      for (int r = 0; r < 4; r++) p[r * 12] += acc[fm][fn][r];
    }
  }
}

// ---------------------------------------------------------------------------
extern "C" void kernel_launch(void* const* d_in, const int* in_sizes, int n_in,
                              void* d_out, int out_size, void* d_ws, size_t ws_size,
                              hipStream_t stream) {
  const float* x = (const float*)d_in[0];
  const float* support = (const float*)d_in[1];
  const float* W0 = (const float*)d_in[2];
  const float* b0 = (const float*)d_in[3];
  const float* Ws = (const float*)d_in[4];
  const float* bs = (const float*)d_in[5];
  const float* Wf = (const float*)d_in[6];
  const float* bf = (const float*)d_in[7];
  float* out = (float*)d_out;
  char* ws = (char*)d_ws;

  float* stats = (float*)ws;                              // 49152*12*4 = 2,359,296 B
  float* D = (float*)(ws + 2359296);                      // 16,384 B
  float* cb = (float*)(ws + 2375680);                     // 256 B
  unsigned short* Gt = (unsigned short*)(ws + 2375936);   // 98,304 B
  const size_t fixed_end = 2474240;
  const size_t szY = 18874368;  // per n
  const size_t szA = 25165824;  // per n

  int C = 1;
  if (ws_size > fixed_end) {
    size_t remb = ws_size - fixed_end;
    size_t c = remb / (szY + szA);
    if (c > 16) c = 16;
    if (c < 1) c = 1;
    C = (int)c;
  }
  unsigned short* Ybuf = (unsigned short*)(ws + fixed_end);
  unsigned short* Abuf = (unsigned short*)(ws + fixed_end + (size_t)C * szY);

  k_prep<<<13, 256, 0, stream>>>(W0, b0, Ws, bs, Wf, bf, D, cb, Gt);
  k_stats<<<12288, 256, 0, stream>>>(support, stats);
  k_init<<<16384, 256, 0, stream>>>(x, D, cb, out);
  for (int s = 0; s < 16; s += C) {
    int Cc = (16 - s) < C ? (16 - s) : C;
    k_ybuild<<<Cc * 96, 256, 0, stream>>>(x, Gt, Ybuf, s);
    k_buildA<<<Cc * 3072, 256, 0, stream>>>(support, stats, Abuf, s);
    k_biggemm<<<Cc * 48, 256, 0, stream>>>(Abuf, Ybuf, out, s);
  }
}

// Round 8
// 1112.395 us; speedup vs baseline: 1.1538x; 1.0193x over previous
//
#include <hip/hip_runtime.h>
#include <hip/hip_bf16.h>
#include <hip/hip_fp16.h>

// Problem constants
// x: (16,64,1024,12) f32, support: (16,3,1024,1024) f32
// out: (16,64,1024,12) f32
#define NB 16
#define V 1024
#define LL 12
#define C64 64
#define SL 3
#define CL 768        // 64*12
#define KTOT 12288    // 12*1024
#define MARKOFF -1e20f

typedef _Float16 f16x8 __attribute__((ext_vector_type(8)));
typedef __attribute__((ext_vector_type(4))) float f32x4;

// fp32 -> fp16 bits (RN). All quantized tensors (x, G, Y, A) are
// small-magnitude; fp16 gives 8x lower rounding error than bf16 at the same
// MFMA rate.
static __device__ __forceinline__ unsigned short f2h(float f) {
  __half h = __float2half(f);
  return __builtin_bit_cast(unsigned short, h);
}

// async global->LDS direct staging, 16B per lane.
// LDS dest must be wave-uniform base + lane*16 (it is: byte offset = t*16).
typedef const __attribute__((address_space(1))) unsigned int gas_u32;
typedef __attribute__((address_space(3))) unsigned int las_u32;
static __device__ __forceinline__ void gld16(const void* g, void* l) {
  __builtin_amdgcn_global_load_lds((gas_u32*)g, (las_u32*)l, 16, 0, 0);
}

// 64-bit cross-lane helpers (2x32-bit shuffles)
static __device__ __forceinline__ unsigned long long shflx64(unsigned long long v, int m) {
  unsigned lo = __shfl_xor((unsigned)v, m);
  unsigned hi = __shfl_xor((unsigned)(v >> 32), m);
  return ((unsigned long long)hi << 32) | lo;
}
static __device__ __forceinline__ unsigned long long shfl64get(unsigned long long v, int srcLane) {
  unsigned lo = __shfl((unsigned)v, srcLane);
  unsigned hi = __shfl((unsigned)(v >> 32), srcLane);
  return ((unsigned long long)hi << 32) | lo;
}
// monotone key <-> float
static __device__ __forceinline__ float k2f(unsigned kk) {
  unsigned u = (kk & 0x80000000u) ? (kk & 0x7FFFFFFFu) : ~kk;
  return __uint_as_float(u);
}

// ---------------------------------------------------------------------------
// k_prep: D = F0*W0 (fp32), Gt[(ig*64+o)][c] = fp16( sum_c2 Wf[o,64(i+1)+c2]*Ws[i][c2][64g+c] ),
//         cb[o] = bf[o] + F0*b0 + sum_i F_{i+1}*bs[i]
__global__ __launch_bounds__(256) void k_prep(const float* __restrict__ W0,
                                              const float* __restrict__ b0,
                                              const float* __restrict__ Ws,
                                              const float* __restrict__ bs,
                                              const float* __restrict__ Wf,
                                              const float* __restrict__ bf,
                                              float* __restrict__ D,
                                              float* __restrict__ cb,
                                              unsigned short* __restrict__ Gt) {
  int b = blockIdx.x;
  int t = threadIdx.x;
  int o = t >> 2, cp = t & 3;
  if (b < 12) {
    int i = b >> 2, g = b & 3;
    for (int c = cp * 16; c < cp * 16 + 16; c++) {
      float acc = 0.f;
      for (int c2 = 0; c2 < 64; c2++)
        acc += Wf[o * 256 + 64 * (i + 1) + c2] * Ws[i * 16384 + c2 * 256 + g * 64 + c];
      Gt[(size_t)(b * 64 + o) * 64 + c] = f2h(acc);
    }
  } else {
    for (int c = cp * 16; c < cp * 16 + 16; c++) {
      float acc = 0.f;
      for (int c2 = 0; c2 < 64; c2++)
        acc += Wf[o * 256 + c2] * W0[c2 * 64 + c];
      D[o * 64 + c] = acc;
    }
    if (t < 64) {
      float acc = bf[t];
      for (int c2 = 0; c2 < 64; c2++) acc += Wf[t * 256 + c2] * b0[c2];
      for (int i = 0; i < 3; i++)
        for (int c2 = 0; c2 < 64; c2++) acc += Wf[t * 256 + 64 * (i + 1) + c2] * bs[i * 64 + c2];
      cb[t] = acc;
    }
  }
}

// ---------------------------------------------------------------------------
// k_stats v2: ONE WAVE PER ROW, barrier-light, atomic-free, histogram-free.
__global__ __launch_bounds__(256) void k_stats(const float* __restrict__ support,
                                               float* __restrict__ stats) {
  int t = threadIdx.x;
  int lane = t & 63, wid = t >> 6;
  int row = blockIdx.x * 4 + wid;  // (n*3+i)*1024 + v
  const float* a = support + (size_t)row * 1024;

  __shared__ unsigned long long cand[4][128];

  float va[16];
  const float4* a4 = (const float4*)a;
#pragma unroll
  for (int j = 0; j < 4; j++) {
    float4 f = a4[lane + 64 * j];
    va[j * 4 + 0] = f.x; va[j * 4 + 1] = f.y; va[j * 4 + 2] = f.z; va[j * 4 + 3] = f.w;
  }

  float m = va[0];
#pragma unroll
  for (int q = 1; q < 16; q++) m = fmaxf(m, va[q]);
#pragma unroll
  for (int off = 32; off; off >>= 1) m = fmaxf(m, __shfl_xor(m, off));

  float zf = 0.f;
#pragma unroll
  for (int q = 0; q < 16; q++) zf += __expf(va[q] - m);
#pragma unroll
  for (int off = 32; off; off >>= 1) zf += __shfl_xor(zf, off);

  unsigned ky[16];
#pragma unroll
  for (int q = 0; q < 16; q++) {
    unsigned u = __float_as_uint(va[q]);
    ky[q] = (u & 0x80000000u) ? ~u : (u | 0x80000000u);
  }

  unsigned Klo = 0u, Khi = 0xFFFFFFFFu;
  unsigned K = 0xBFB33333u;  // key(1.4f) seed
  int c = 0;
  bool ok = false;
  for (int it = 0; it < 40; ++it) {
    int cl = 0;
#pragma unroll
    for (int q = 0; q < 16; q++) cl += (ky[q] > K) ? 1 : 0;
    c = cl;
#pragma unroll
    for (int off = 32; off; off >>= 1) c += __shfl_xor(c, off);
    if (c >= 40 && c <= 128) { ok = true; break; }
    if (c > 128) Klo = K; else Khi = K;
    if (Khi - Klo <= 1u) break;
    K = Klo + ((Khi - Klo) >> 1);
  }
  bool special = !ok;
  if (special) {
    K = Khi;
    int cl = 0;
#pragma unroll
    for (int q = 0; q < 16; q++) cl += (ky[q] > K) ? 1 : 0;
    c = cl;
#pragma unroll
    for (int off = 32; off; off >>= 1) c += __shfl_xor(c, off);
  }

  int cl = 0;
#pragma unroll
  for (int q = 0; q < 16; q++) cl += (ky[q] > K) ? 1 : 0;
  int pre = cl;
#pragma unroll
  for (int off = 1; off < 64; off <<= 1) {
    int t2 = __shfl_up(pre, off);
    if (lane >= off) pre += t2;
  }
  int o = pre - cl;
  cand[wid][lane] = 0ull;
  cand[wid][64 + lane] = 0ull;
  __syncthreads();
#pragma unroll
  for (int q = 0; q < 16; q++) {
    if (ky[q] > K) {
      unsigned idx = (unsigned)(lane * 4 + (q >> 2) * 256 + (q & 3));
      cand[wid][o++] = ((unsigned long long)ky[q] << 32) | (unsigned)(~idx);
    }
  }
  __syncthreads();
  unsigned long long s0 = cand[wid][lane];
  unsigned long long s1 = cand[wid][64 + lane];

#pragma unroll
  for (int k2 = 2; k2 <= 128; k2 <<= 1) {
#pragma unroll
    for (int j = k2 >> 1; j > 0; j >>= 1) {
      if (j == 64) {
        unsigned long long mx = (s0 > s1) ? s0 : s1;
        unsigned long long mn = (s0 > s1) ? s1 : s0;
        s0 = mx; s1 = mn;
      } else {
        bool lower = ((lane & j) == 0);
        bool d0 = ((lane & k2) == 0);
        bool d1 = (((64 + lane) & k2) == 0);
        unsigned long long q0 = shflx64(s0, j);
        unsigned long long q1 = shflx64(s1, j);
        bool kmax0 = (lower == d0);
        bool kmax1 = (lower == d1);
        s0 = (kmax0 == (s0 > q0)) ? s0 : q0;
        s1 = (kmax1 == (s1 > q1)) ? s1 : q1;
      }
    }
  }

  int nval = (c < 40) ? c : 40;
  float pv = 0.f;
  if (lane < nval) pv = __expf(k2f((unsigned)(s0 >> 32)) - m);
  float z10 = (lane < 10) ? pv : 0.f;
  float z20 = (lane < 20) ? pv : 0.f;
  float z40 = pv;
#pragma unroll
  for (int off = 32; off; off >>= 1) {
    z10 += __shfl_xor(z10, off);
    z20 += __shfl_xor(z20, off);
    z40 += __shfl_xor(z40, off);
  }

  float T[3], wcut[3], iZ[3];
  const int kk3[3] = {10, 20, 40};
#pragma unroll
  for (int s3 = 0; s3 < 3; s3++) {
    int k = kk3[s3];
    if (!special || k <= c) {
      unsigned long long sk = shfl64get(s0, k - 1);
      T[s3] = k2f((unsigned)(sk >> 32));
      wcut[s3] = (float)(~(unsigned)sk);
      float Zk = (s3 == 0) ? z10 : ((s3 == 1) ? z20 : z40);
      iZ[s3] = 1.f / Zk;
    } else {
      int r = k - c;
      float vt = k2f(K);
      T[s3] = vt;
      int lo2 = -1, hi2 = 1023;
      while (hi2 - lo2 > 1) {
        int mid = (lo2 + hi2) >> 1;
        int cnt = 0;
#pragma unroll
        for (int q = 0; q < 16; q++) {
          int idx = lane * 4 + (q >> 2) * 256 + (q & 3);
          cnt += (ky[q] == K && idx <= mid) ? 1 : 0;
        }
#pragma unroll
        for (int off = 32; off; off >>= 1) cnt += __shfl_xor(cnt, off);
        if (cnt >= r) hi2 = mid; else lo2 = mid;
      }
      wcut[s3] = (float)hi2;
      iZ[s3] = 1.f / (z40 + (float)r * __expf(vt - m));
    }
  }

  if (lane == 0) {
    float* sp = stats + (size_t)row * 12;
    float4 w0v = {m, 1.f / zf, T[0], T[1]};
    float4 w1v = {T[2], iZ[0], iZ[1], iZ[2]};
    float4 w2v = {wcut[0], wcut[1], wcut[2], 0.f};
    *(float4*)(sp + 0) = w0v;
    *(float4*)(sp + 4) = w1v;
    *(float4*)(sp + 8) = w2v;
  }
}

// ---------------------------------------------------------------------------
// k_init v2: out[n,o,w,l] = cb[o] + sum_c D[o,c] * x[n,c,w,l]  (fp32 direct)
// xs transposed to [l][c] (pad 68: 16B-aligned rows, <=2-way banks) and Ds
// padded to 68 so the c-loop runs on ds_read_b128 pairs (4x fewer LDS instrs
// than the scalar version; Ds reads are ~6-distinct-rows/wave => broadcast).
__global__ __launch_bounds__(256) void k_init(const float* __restrict__ x,
                                              const float* __restrict__ D,
                                              const float* __restrict__ cb,
                                              float* __restrict__ out) {
  int b = blockIdx.x;
  int n = b >> 10, w = b & 1023;
  int t = threadIdx.x;
  __shared__ __align__(16) float xs[12 * 68];
  __shared__ __align__(16) float Ds[64 * 68];
  __shared__ float cbs[64];
  const float* xb = x + (size_t)n * 786432 + w * 12;
  for (int u = t; u < 768; u += 256) {
    int c = u / 12, l2 = u - c * 12;
    xs[l2 * 68 + c] = xb[(size_t)c * 12288 + l2];
  }
  for (int u = t; u < 4096; u += 256) Ds[(u >> 6) * 68 + (u & 63)] = D[u];
  if (t < 64) cbs[t] = cb[t];
  __syncthreads();
  float* ob = out + (size_t)n * 786432 + w * 12;
  for (int u = t; u < 768; u += 256) {
    int o = u / 12, l2 = u - o * 12;
    float accv = cbs[o];
    const float4* dr = (const float4*)&Ds[o * 68];
    const float4* xr = (const float4*)&xs[l2 * 68];
#pragma unroll
    for (int c4 = 0; c4 < 16; c4++) {
      float4 d = dr[c4];
      float4 xv = xr[c4];
      accv += d.x * xv.x + d.y * xv.y + d.z * xv.z + d.w * xv.w;
    }
    ob[(size_t)o * 12288 + l2] = accv;
  }
}

// ---------------------------------------------------------------------------
// k_ybuild v2: one block per (nc, mt); x-slice staged ONCE, A-fragments held
// in registers across the nt loop (x reads and f2h work cut 6x). Per nt:
// stage Gt tile via gld16, MFMA, reorder, coalesced store.
__global__ __launch_bounds__(256) void k_ybuild(const float* __restrict__ x,
                                                const unsigned short* __restrict__ Gt,
                                                unsigned short* __restrict__ Y,
                                                int s) {
  int b = blockIdx.x;
  int nc = b / 96;
  int mt = b - nc * 96;
  int n = s + nc;
  int l = mt >> 3;
  int v0 = (mt & 7) << 7;

  __shared__ __align__(16) char smem[34816];
  unsigned short* A2 = (unsigned short*)smem;   // [2][128][32] flat, 16KB
  unsigned short* B2 = (unsigned short*)smem;   // [2][128][32] flat, 16KB (reuse)
  unsigned short(*R)[136] = (unsigned short(*)[136])smem;  // 34816B (reuse)

  int t = threadIdx.x;
  int lane = t & 63, wid = t >> 6;
  int wm = (wid >> 1) * 64, wn = (wid & 1) * 64;
  int ko = (lane >> 4) * 8;
  int mrow = lane & 15;

  // stage A: x[n][c][v0+mloc][l] for c in [half*32, half*32+32)
  {
    int mloc = t >> 1, half = t & 1;
    const float* xp = x + (size_t)n * 786432 + (size_t)(half * 32) * 12288 + (size_t)(v0 + mloc) * 12 + l;
#pragma unroll
    for (int sg = 0; sg < 4; sg++) {
      unsigned q0 = f2h(xp[(size_t)(sg * 8 + 0) * 12288]) | ((unsigned)f2h(xp[(size_t)(sg * 8 + 1) * 12288]) << 16);
      unsigned q1 = f2h(xp[(size_t)(sg * 8 + 2) * 12288]) | ((unsigned)f2h(xp[(size_t)(sg * 8 + 3) * 12288]) << 16);
      unsigned q2 = f2h(xp[(size_t)(sg * 8 + 4) * 12288]) | ((unsigned)f2h(xp[(size_t)(sg * 8 + 5) * 12288]) << 16);
      unsigned q3 = f2h(xp[(size_t)(sg * 8 + 6) * 12288]) | ((unsigned)f2h(xp[(size_t)(sg * 8 + 7) * 12288]) << 16);
      uint4 q = {q0, q1, q2, q3};
      *(uint4*)&A2[(size_t)half * 4096 + (size_t)mloc * 32 + sg * 8] = q;
    }
  }
  __syncthreads();

  // hoist this wave's A-fragments to registers (valid for all nt)
  f16x8 af[2][4];
#pragma unroll
  for (int half = 0; half < 2; half++)
#pragma unroll
    for (int fm = 0; fm < 4; fm++)
      af[half][fm] = *(const f16x8*)(A2 + half * 4096 + (wm + fm * 16 + mrow) * 32 + ko);
  __syncthreads();  // lgkm drained by the implicit waitcnt; A2 region now free

  // per-thread gld16 source decomposition for B2 chunks d = t + 256*i
  const unsigned short* gG[4];
#pragma unroll
  for (int i = 0; i < 4; i++) {
    int d = t + 256 * i;
    int half = d >> 9, row = (d >> 2) & 127, sg = d & 3;
    gG[i] = Gt + (size_t)row * 64 + half * 32 + sg * 8;
  }

  for (int nt = 0; nt < 6; nt++) {
    // stage B2: Gt rows nt*128..+128 (column-major halves), linear LDS dest
#pragma unroll
    for (int i = 0; i < 4; i++)
      gld16(gG[i] + (size_t)nt * 8192, smem + ((size_t)t + 256 * i) * 16);
    __syncthreads();  // drains vmcnt(0): B2 resident

    f32x4 acc[4][4];
#pragma unroll
    for (int fm = 0; fm < 4; fm++)
#pragma unroll
      for (int fn = 0; fn < 4; fn++) acc[fm][fn] = (f32x4){0.f, 0.f, 0.f, 0.f};

#pragma unroll
    for (int half = 0; half < 2; half++) {
      f16x8 bfr[4];
#pragma unroll
      for (int fn = 0; fn < 4; fn++)
        bfr[fn] = *(const f16x8*)(B2 + half * 4096 + (wn + fn * 16 + mrow) * 32 + ko);
#pragma unroll
      for (int fm = 0; fm < 4; fm++)
#pragma unroll
        for (int fn = 0; fn < 4; fn++)
          acc[fm][fn] = __builtin_amdgcn_mfma_f32_16x16x32_f16(af[half][fm], bfr[fn], acc[fm][fn], 0, 0, 0);
    }
    __syncthreads();  // B2 dead; R may overwrite

    // reorder into R[col][m] (m = v offset), 4 consecutive rows per frag-reg
#pragma unroll
    for (int fm = 0; fm < 4; fm++)
#pragma unroll
      for (int fn = 0; fn < 4; fn++) {
        int col = wn + fn * 16 + mrow;
        int mr = wm + fm * 16 + (lane >> 4) * 4;
        unsigned lo = (unsigned)f2h(acc[fm][fn][0]) | ((unsigned)f2h(acc[fm][fn][1]) << 16);
        unsigned hi = (unsigned)f2h(acc[fm][fn][2]) | ((unsigned)f2h(acc[fm][fn][3]) << 16);
        uint2 pk = {lo, hi};
        *(uint2*)&R[col][mr] = pk;
      }
    __syncthreads();

    // coalesced output: row = ncol-local, 128 v contiguous
    {
      int row = t >> 1, hseg = t & 1;
      int ncol = nt * 128 + row;
      int ig = ncol >> 6, o = ncol & 63;
      size_t gbase = ((size_t)nc * 768 + (size_t)(o * 12 + l)) * 12288 + (size_t)ig * 1024 + v0 + hseg * 64;
#pragma unroll
      for (int sg = 0; sg < 8; sg++)
        *(uint4*)(Y + gbase + sg * 8) = *(const uint4*)&R[row][hseg * 64 + sg * 8];
    }
    __syncthreads();  // all R reads done before next nt's B2 stage
  }
}

// ---------------------------------------------------------------------------
// k_buildA v2: tile = 32 w x 64 v (half the blocks). Per thread 8 v => each
// (w,g) write is a contiguous 128B uint4 segment (was 64B); reads stay 128B.
// Per-element math identical to v1 (bit-identical Abuf).
__global__ __launch_bounds__(256) void k_buildA(const float* __restrict__ support,
                                                const float* __restrict__ stats,
                                                unsigned short* __restrict__ Abuf,
                                                int s) {
  int b = blockIdx.x;
  int nc = b / 1536;
  int rem = b - nc * 1536;
  int i = rem >> 9;            // 0..2
  int tile = rem & 511;
  int v0 = (tile >> 5) << 6;   // 16 v-tiles of 64
  int w0 = (tile & 31) << 5;   // 32 w-tiles of 32
  int n = s + nc;
  const float* sup = support + (size_t)(n * 3 + i) * 1048576;
  const float* stb = stats + (size_t)(n * 3 + i) * 12288;

  __shared__ float S[64][33];
  __shared__ float st[64][12];
  int t = threadIdx.x;
  {
    int vl = t >> 2, wseg = t & 3;  // 64 v-rows, 8 w-floats per thread
    const float* p = sup + (size_t)(v0 + vl) * 1024 + w0 + wseg * 8;
    float4 f0 = *(const float4*)p;
    float4 f1 = *(const float4*)(p + 4);
    int cb0 = wseg * 8;
    S[vl][cb0 + 0] = f0.x; S[vl][cb0 + 1] = f0.y;
    S[vl][cb0 + 2] = f0.z; S[vl][cb0 + 3] = f0.w;
    S[vl][cb0 + 4] = f1.x; S[vl][cb0 + 5] = f1.y;
    S[vl][cb0 + 6] = f1.z; S[vl][cb0 + 7] = f1.w;
  }
  for (int u = t; u < 768; u += 256) {
    int vl = u / 12, q = u - vl * 12;
    st[vl][q] = stb[(size_t)(v0 + vl) * 12 + q];
  }
  __syncthreads();

  int w_loc = t >> 3, vseg = t & 7;
  float wg = (float)(w0 + w_loc);
  unsigned short bv[4][8];
#pragma unroll
  for (int j = 0; j < 8; j++) {
    int vl = vseg * 8 + j;
    float aa = S[vl][w_loc];
    float m = st[vl][0], izf = st[vl][1];
    float T10 = st[vl][2], T20 = st[vl][3], T40 = st[vl][4];
    float iz10 = st[vl][5], iz20 = st[vl][6], iz40 = st[vl][7];
    float w10 = st[vl][8], w20 = st[vl][9], w40 = st[vl][10];
    float ee = __expf(aa - m);
    bool in10 = (aa > T10) || (aa == T10 && wg <= w10);
    bool in20 = (aa > T20) || (aa == T20 && wg <= w20);
    bool in40 = (aa > T40) || (aa == T40 && wg <= w40);
    bv[3][j] = f2h(ee * izf);
    bv[2][j] = f2h(in40 ? ee * iz40 : 0.f);
    bv[1][j] = f2h(in20 ? ee * iz20 : 0.f);
    bv[0][j] = f2h(in10 ? ee * iz10 : 0.f);
  }
  size_t base = ((size_t)nc * 1024 + w0 + w_loc) * 12288 + (size_t)i * 4096 + v0 + vseg * 8;
#pragma unroll
  for (int g = 0; g < 4; g++) {
    uint4 pk;
    pk.x = (unsigned)bv[g][0] | ((unsigned)bv[g][1] << 16);
    pk.y = (unsigned)bv[g][2] | ((unsigned)bv[g][3] << 16);
    pk.z = (unsigned)bv[g][4] | ((unsigned)bv[g][5] << 16);
    pk.w = (unsigned)bv[g][6] | ((unsigned)bv[g][7] << 16);
    *(uint4*)(Abuf + base + (size_t)g * 1024) = pk;
  }
}

// ---------------------------------------------------------------------------
// k_biggemm v7 (best: 425us): round-2 skeleton (128x128, BK=32, 16KB LDS,
// gld16 direct staging, 2 barriers/K-step) + chunk-rotation swizzle folded
// into pre-loop setup (bank-conflict 0, zero loop-instruction cost).
__global__ __launch_bounds__(256) void k_biggemm(const unsigned short* __restrict__ A,
                                                 const unsigned short* __restrict__ Y,
                                                 float* __restrict__ out,
                                                 int s) {
  // XCD swizzle: grid = Cc*48, always % 8 == 0 -> simple bijective remap.
  int b = blockIdx.x;
  int cpx = gridDim.x >> 3;
  b = (b & 7) * cpx + (b >> 3);

  int nc = b / 48;
  int rem2 = b - nc * 48;
  int mt = rem2 / 6, nt = rem2 - (rem2 / 6) * 6;
  int n = s + nc;

  __shared__ __align__(16) unsigned short A3[128][32];
  __shared__ __align__(16) unsigned short B3[128][32];

  int t = threadIdx.x;
  int lane = t & 63, wid = t >> 6;
  int wm = (wid >> 1) * 64, wn = (wid & 1) * 64;

  const unsigned short* Ab = A + (size_t)nc * 12582912 + (size_t)(mt * 128) * 12288;
  const unsigned short* Yb = Y + (size_t)nc * 9437184 + (size_t)(nt * 128) * 12288;

  // staging map with inverse rotation (see r7 notes)
  int srow = t >> 2;
  int scc = ((t & 3) - ((t >> 3) & 3)) & 3;
  const unsigned short* gA0 = Ab + (size_t)srow * 12288 + scc * 8;
  const unsigned short* gA1 = gA0 + (size_t)64 * 12288;
  const unsigned short* gB0 = Yb + (size_t)srow * 12288 + scc * 8;
  const unsigned short* gB1 = gB0 + (size_t)64 * 12288;
  unsigned short* lA0 = &A3[0][0] + (size_t)t * 8;
  unsigned short* lA1 = lA0 + 2048;
  unsigned short* lB0 = &B3[0][0] + (size_t)t * 8;
  unsigned short* lB1 = lB0 + 2048;

  f32x4 acc[4][4];
#pragma unroll
  for (int fm = 0; fm < 4; fm++)
#pragma unroll
    for (int fn = 0; fn < 4; fn++) acc[fm][fn] = (f32x4){0.f, 0.f, 0.f, 0.f};

  // rotated read offset (replaces ko)
  int cpo = (((lane >> 4) + ((lane >> 1) & 3)) & 3) * 8;

  for (int kt = 0; kt < 384; kt++) {
    __syncthreads();  // previous step's ds_reads done before DMA overwrites LDS
    gld16(gA0, lA0);
    gld16(gA1, lA1);
    gld16(gB0, lB0);
    gld16(gB1, lB1);
    gA0 += 32; gA1 += 32; gB0 += 32; gB1 += 32;
    __syncthreads();  // vmcnt(0) drain before s_barrier -> tile ready
    f16x8 af[4], bfr[4];
#pragma unroll
    for (int fm = 0; fm < 4; fm++) af[fm] = *(const f16x8*)&A3[wm + fm * 16 + (lane & 15)][cpo];
#pragma unroll
    for (int fn = 0; fn < 4; fn++) bfr[fn] = *(const f16x8*)&B3[wn + fn * 16 + (lane & 15)][cpo];
#pragma unroll
    for (int fm = 0; fm < 4; fm++)
#pragma unroll
      for (int fn = 0; fn < 4; fn++)
        acc[fm][fn] = __builtin_amdgcn_mfma_f32_16x16x32_f16(af[fm], bfr[fn], acc[fm][fn], 0, 0, 0);
  }

  // epilogue: RMW into out (tiles are exclusive)
  float* ob = out + (size_t)n * 786432;
#pragma unroll
  for (int fn = 0; fn < 4; fn++) {
    int col = nt * 128 + wn + fn * 16 + (lane & 15);  // = o*12 + l
    int oo = col / 12;
    int ll2 = col - oo * 12;
    float* cbase = ob + (size_t)oo * 12288 + ll2;
#pragma unroll
    for (int fm = 0; fm < 4; fm++) {
      int w = mt * 128 + wm + fm * 16 + (lane >> 4) * 4;
      float* p = cbase + (size_t)w * 12;
#pragma unroll
      for (int r = 0; r < 4; r++) p[r * 12] += acc[fm][fn][r];
    }
  }
}

// ---------------------------------------------------------------------------
extern "C" void kernel_launch(void* const* d_in, const int* in_sizes, int n_in,
                              void* d_out, int out_size, void* d_ws, size_t ws_size,
                              hipStream_t stream) {
  const float* x = (const float*)d_in[0];
  const float* support = (const float*)d_in[1];
  const float* W0 = (const float*)d_in[2];
  const float* b0 = (const float*)d_in[3];
  const float* Ws = (const float*)d_in[4];
  const float* bs = (const float*)d_in[5];
  const float* Wf = (const float*)d_in[6];
  const float* bf = (const float*)d_in[7];
  float* out = (float*)d_out;
  char* ws = (char*)d_ws;

  float* stats = (float*)ws;                              // 49152*12*4 = 2,359,296 B
  float* D = (float*)(ws + 2359296);                      // 16,384 B
  float* cb = (float*)(ws + 2375680);                     // 256 B
  unsigned short* Gt = (unsigned short*)(ws + 2375936);   // 98,304 B
  const size_t fixed_end = 2474240;
  const size_t szY = 18874368;  // per n
  const size_t szA = 25165824;  // per n

  int C = 1;
  if (ws_size > fixed_end) {
    size_t remb = ws_size - fixed_end;
    size_t c = remb / (szY + szA);
    if (c > 16) c = 16;
    if (c < 1) c = 1;
    C = (int)c;
  }
  unsigned short* Ybuf = (unsigned short*)(ws + fixed_end);
  unsigned short* Abuf = (unsigned short*)(ws + fixed_end + (size_t)C * szY);

  k_prep<<<13, 256, 0, stream>>>(W0, b0, Ws, bs, Wf, bf, D, cb, Gt);
  k_stats<<<12288, 256, 0, stream>>>(support, stats);
  k_init<<<16384, 256, 0, stream>>>(x, D, cb, out);
  for (int s = 0; s < 16; s += C) {
    int Cc = (16 - s) < C ? (16 - s) : C;
    k_ybuild<<<Cc * 96, 256, 0, stream>>>(x, Gt, Ybuf, s);
    k_buildA<<<Cc * 1536, 256, 0, stream>>>(support, stats, Abuf, s);
    k_biggemm<<<Cc * 48, 256, 0, stream>>>(Abuf, Ybuf, out, s);
  }
}